// Round 1
// baseline (287.328 us; speedup 1.0000x reference)
//
#include <hip/hip_runtime.h>

// MeanAggregator: out[b,:] = mean over DISTINCT nbrs[b,:] of features[idx,:]
// features: [N=200000, D=256] f32; nbrs: [B=32768, S=10] int; out: [B, 256] f32
//
// Strategy: one wave (64 lanes) per output row. Lane i owns float4 at
// columns [4i, 4i+4). A feature-row read is one fully-coalesced 1KB wave
// access (global_load_dwordx4 per lane). Dedupe weights (first occurrence
// counts once) computed redundantly per-lane in registers; loads are
// unconditional + weighted so all 10 gathers issue back-to-back (MLP).

#define AGG_S 10
#define AGG_D 256

__global__ __launch_bounds__(256) void MeanAggregator_58514634441194_kernel(
    const float* __restrict__ feat,
    const int* __restrict__ nbrs,
    float* __restrict__ out,
    int B)
{
    const int wave = (blockIdx.x * blockDim.x + threadIdx.x) >> 6;  // row id
    const int lane = threadIdx.x & 63;
    if (wave >= B) return;

    // Load this row's 10 neighbor indices. Address is the same across the
    // wave -> same-address loads broadcast from cache; cheap.
    const int* __restrict__ row = nbrs + (size_t)wave * AGG_S;
    int idx[AGG_S];
#pragma unroll
    for (int s = 0; s < AGG_S; ++s) idx[s] = row[s];

    // First-occurrence weights: w[s] = 0 if idx[s] appeared at some j < s.
    float w[AGG_S];
    float cnt = 0.0f;
#pragma unroll
    for (int s = 0; s < AGG_S; ++s) {
        bool dup = false;
#pragma unroll
        for (int j = 0; j < AGG_S; ++j) {
            if (j < s) dup |= (idx[j] == idx[s]);
        }
        w[s] = dup ? 0.0f : 1.0f;
        cnt += w[s];
    }

    // Gather + weighted accumulate. All 10 loads are independent.
    float4 acc = make_float4(0.f, 0.f, 0.f, 0.f);
#pragma unroll
    for (int s = 0; s < AGG_S; ++s) {
        const float4* __restrict__ fr =
            (const float4*)(feat + (size_t)idx[s] * AGG_D);
        float4 v = fr[lane];
        acc.x += w[s] * v.x;
        acc.y += w[s] * v.y;
        acc.z += w[s] * v.z;
        acc.w += w[s] * v.w;
    }

    const float inv = 1.0f / cnt;
    acc.x *= inv; acc.y *= inv; acc.z *= inv; acc.w *= inv;

    ((float4*)(out + (size_t)wave * AGG_D))[lane] = acc;
}

extern "C" void kernel_launch(void* const* d_in, const int* in_sizes, int n_in,
                              void* d_out, int out_size, void* d_ws, size_t ws_size,
                              hipStream_t stream)
{
    const float* feat = (const float*)d_in[0];
    const int*   nbrs = (const int*)d_in[1];
    float*       out  = (float*)d_out;

    const int B = in_sizes[1] / AGG_S;           // 32768
    const int threads = 256;                     // 4 waves/block
    const int rows_per_block = threads / 64;
    const int blocks = (B + rows_per_block - 1) / rows_per_block;

    MeanAggregator_58514634441194_kernel<<<blocks, threads, 0, stream>>>(
        feat, nbrs, out, B);
}